// Round 7
// baseline (315.059 us; speedup 1.0000x reference)
//
#include <hip/hip_runtime.h>
#include <math.h>

// VectorQuantizer: N=131072 tokens, K=1024 codes, D=64, fp32.
// Out layout (flat): z_q_st[N*D] | loss | perplexity | indices[N] (as f32)
#define NTOK 131072
#define NEMB 1024
#define DIM  64
#define OUT_LOSS (NTOK * DIM)
#define OUT_PERP (OUT_LOSS + 1)
#define OUT_IDX  (OUT_LOSS + 2)

#define EPS_FLAG 6e-5f   // screen ambiguity margin (frozen; passed r3-r6)

typedef short bf16x8 __attribute__((ext_vector_type(8)));
typedef float f32x4  __attribute__((ext_vector_type(4)));

// ---- numpy fp32 semantics helpers (frozen from round 2 -- PASSED) ----------
__device__ __forceinline__ float sqb(float x) {
    float y = x * x;
    asm volatile("" : "+v"(y));
    return y;
}
// numpy pairwise_sum for n=64 contiguous: 8 accumulators stride 8, then
// ((r0+r1)+(r2+r3))+((r4+r5)+(r6+r7)).
#define NP_PAIRWISE_SQ64(GET, RES)                                     \
    do {                                                               \
        float r0 = sqb(GET(0)), r1 = sqb(GET(1)), r2 = sqb(GET(2)),    \
              r3 = sqb(GET(3)), r4 = sqb(GET(4)), r5 = sqb(GET(5)),    \
              r6 = sqb(GET(6)), r7 = sqb(GET(7));                      \
        _Pragma("unroll")                                              \
        for (int i = 8; i < 64; i += 8) {                              \
            r0 += sqb(GET(i + 0)); r1 += sqb(GET(i + 1));              \
            r2 += sqb(GET(i + 2)); r3 += sqb(GET(i + 3));              \
            r4 += sqb(GET(i + 4)); r5 += sqb(GET(i + 5));              \
            r6 += sqb(GET(i + 6)); r7 += sqb(GET(i + 7));              \
        }                                                              \
        RES = ((r0 + r1) + (r2 + r3)) + ((r4 + r5) + (r6 + r7));       \
    } while (0)

__device__ __forceinline__ unsigned short f2bf_rne(float x) {
    unsigned u = __float_as_uint(x);
    u += 0x7FFFu + ((u >> 16) & 1u);   // round-to-nearest-even
    return (unsigned short)(u >> 16);
}
__device__ __forceinline__ float bf2f(unsigned short b) {
    return __uint_as_float(((unsigned)b) << 16);
}

// ws layout (bytes):
//   0:      sse double
//   64:     counts int[1024]
//   4160:   done int
//   4224:   h float[1024]
//   8320:   ch bf16[1024*64]   (128 KiB)
//   139392: cl bf16[1024*64]   (128 KiB)
//   270464: cbT float[64*1024] (256 KiB, transposed codebook)

// Kernel 0: h[k] np-exact; ch/cl bf16 split of (-2c); cbT transpose;
// block 0 zeroes sse/counts/done.
__global__ void vq_prep(const float* __restrict__ cb, float* __restrict__ h,
                        unsigned short* __restrict__ ch, unsigned short* __restrict__ cl,
                        float* __restrict__ cbT, double* __restrict__ sse,
                        int* __restrict__ counts, int* __restrict__ done) {
    if (blockIdx.x == 0) {
        if (threadIdx.x == 0) { *sse = 0.0; *done = 0; }
        for (int i = threadIdx.x; i < NEMB; i += 256) counts[i] = 0;
    }
    int k = blockIdx.x * 256 + threadIdx.x;
    if (k >= NEMB) return;
    float c[64];
    const float4* p = (const float4*)(cb + k * DIM);
#pragma unroll
    for (int q = 0; q < 16; ++q) {
        float4 v = p[q];
        c[4 * q] = v.x; c[4 * q + 1] = v.y; c[4 * q + 2] = v.z; c[4 * q + 3] = v.w;
    }
    float hk;
#define GETC(d) (c[d])
    NP_PAIRWISE_SQ64(GETC, hk);
#undef GETC
    h[k] = hk;
#pragma unroll
    for (int d = 0; d < 64; ++d) cbT[d * 1024 + k] = c[d];
#pragma unroll
    for (int b = 0; b < 8; ++b) {
        unsigned uhv[4], ulv[4];
#pragma unroll
        for (int e = 0; e < 4; ++e) {
            float x0 = -2.0f * c[b * 8 + e * 2 + 0];
            float x1 = -2.0f * c[b * 8 + e * 2 + 1];
            unsigned short h0 = f2bf_rne(x0), h1 = f2bf_rne(x1);
            unsigned short l0 = f2bf_rne(x0 - bf2f(h0)), l1 = f2bf_rne(x1 - bf2f(h1));
            uhv[e] = (unsigned)h0 | ((unsigned)h1 << 16);
            ulv[e] = (unsigned)l0 | ((unsigned)l1 << 16);
        }
        *(uint4*)(ch + k * 64 + b * 8) = make_uint4(uhv[0], uhv[1], uhv[2], uhv[3]);
        *(uint4*)(cl + k * 64 + b * 8) = make_uint4(ulv[0], ulv[1], ulv[2], ulv[3]);
    }
}

// Kernel 1: FUSED screen (frozen MFMA numerics) + in-wave exact rescue +
// gather/SSE/histogram + last-block finalize. Block owns 256 tokens.
// LDS map: 0..32767 staging | 32768..33279 h | 33280..35327 zrow[8][64]
//          35328..35391 red double[8] | 35392 flag | (reuse 0.. as double[512])
__global__ __launch_bounds__(512) void vq_fused(
    const float*          __restrict__ ze,
    const float*          __restrict__ cb,
    const unsigned short* __restrict__ ch_g,
    const unsigned short* __restrict__ cl_g,
    const float*          __restrict__ h_g,
    const float*          __restrict__ cbT,
    float*                __restrict__ out,
    double*               __restrict__ sse_g,
    int*                  __restrict__ counts,
    int*                  __restrict__ done) {
    __shared__ __align__(16) char lds[35456];
    const int tid  = threadIdx.x;
    const int lane = tid & 63;
    const int wid  = tid >> 6;
    const int col  = lane & 15;
    const int grp  = lane >> 4;
    const int tbase = blockIdx.x * 256 + wid * 32;

    // ---- Phase 1: MFMA screen (byte-frozen from r3-r6) ----
    bf16x8 zh[2][2], zl[2][2];
#pragma unroll
    for (int tt = 0; tt < 2; ++tt)
#pragma unroll
        for (int s = 0; s < 2; ++s) {
            const float* zp = ze + (size_t)(tbase + tt * 16 + col) * 64 + s * 32 + grp * 8;
            float4 v0 = *(const float4*)(zp);
            float4 v1 = *(const float4*)(zp + 4);
            float zv[8] = {v0.x, v0.y, v0.z, v0.w, v1.x, v1.y, v1.z, v1.w};
            bf16x8 hfr, lfr;
#pragma unroll
            for (int j = 0; j < 8; ++j) {
                unsigned short hb = f2bf_rne(zv[j]);
                unsigned short lb = f2bf_rne(zv[j] - bf2f(hb));
                hfr[j] = (short)hb;
                lfr[j] = (short)lb;
            }
            zh[tt][s] = hfr;
            zl[tt][s] = lfr;
        }

    float m1[2] = {INFINITY, INFINITY}, m2[2] = {INFINITY, INFINITY};
    int   ki[2] = {0, 0};

#define STAGE(cc, b)                                                            \
    do {                                                                        \
        int i = tid;                                                            \
        int4 va = *(const int4*)((const char*)ch_g + (cc) * 8192 + i * 16);     \
        int4 vb = *(const int4*)((const char*)cl_g + (cc) * 8192 + i * 16);     \
        int r = i >> 3, slot = i & 7;                                           \
        int st = r >> 4, row = r & 15;                                          \
        int off = (b) * 16384 + st * 2048 + row * 128 + ((slot ^ (row & 7)) << 4); \
        *(int4*)(lds + off) = va;                                               \
        *(int4*)(lds + off + 8192) = vb;                                        \
        if (i < 64) *(float*)(lds + 32768 + (b) * 256 + i * 4) = h_g[(cc) * 64 + i]; \
    } while (0)

    STAGE(0, 0);
    __syncthreads();

    for (int cc = 0; cc < 16; ++cc) {
        int b = cc & 1;
        if (cc + 1 < 16) STAGE(cc + 1, b ^ 1);

        for (int ct = 0; ct < 4; ++ct) {
            const int arow = b * 16384 + ct * 2048 + col * 128;
            bf16x8 ach0 = *(const bf16x8*)(lds + arow + ((((0 * 4) + grp) ^ (col & 7)) << 4));
            bf16x8 ach1 = *(const bf16x8*)(lds + arow + ((((1 * 4) + grp) ^ (col & 7)) << 4));
            bf16x8 acl0 = *(const bf16x8*)(lds + arow + 8192 + ((((0 * 4) + grp) ^ (col & 7)) << 4));
            bf16x8 acl1 = *(const bf16x8*)(lds + arow + 8192 + ((((1 * 4) + grp) ^ (col & 7)) << 4));
            f32x4 hv = *(const f32x4*)(lds + 32768 + b * 256 + ct * 64 + grp * 16);

            f32x4 acc0 = hv, acc1 = hv;
            acc0 = __builtin_amdgcn_mfma_f32_16x16x32_bf16(ach0, zh[0][0], acc0, 0, 0, 0);
            acc1 = __builtin_amdgcn_mfma_f32_16x16x32_bf16(ach0, zh[1][0], acc1, 0, 0, 0);
            acc0 = __builtin_amdgcn_mfma_f32_16x16x32_bf16(ach1, zh[0][1], acc0, 0, 0, 0);
            acc1 = __builtin_amdgcn_mfma_f32_16x16x32_bf16(ach1, zh[1][1], acc1, 0, 0, 0);
            acc0 = __builtin_amdgcn_mfma_f32_16x16x32_bf16(ach0, zl[0][0], acc0, 0, 0, 0);
            acc1 = __builtin_amdgcn_mfma_f32_16x16x32_bf16(ach0, zl[1][0], acc1, 0, 0, 0);
            acc0 = __builtin_amdgcn_mfma_f32_16x16x32_bf16(ach1, zl[0][1], acc0, 0, 0, 0);
            acc1 = __builtin_amdgcn_mfma_f32_16x16x32_bf16(ach1, zl[1][1], acc1, 0, 0, 0);
            acc0 = __builtin_amdgcn_mfma_f32_16x16x32_bf16(acl0, zh[0][0], acc0, 0, 0, 0);
            acc1 = __builtin_amdgcn_mfma_f32_16x16x32_bf16(acl0, zh[1][0], acc1, 0, 0, 0);
            acc0 = __builtin_amdgcn_mfma_f32_16x16x32_bf16(acl1, zh[0][1], acc0, 0, 0, 0);
            acc1 = __builtin_amdgcn_mfma_f32_16x16x32_bf16(acl1, zh[1][1], acc1, 0, 0, 0);

            const int kb = cc * 64 + ct * 16 + grp * 4;
#pragma unroll
            for (int j = 0; j < 4; ++j) {
                float s0 = acc0[j], s1 = acc1[j];
                bool lt0 = s0 < m1[0], lt1 = s1 < m1[1];
                m2[0] = fminf(m2[0], fmaxf(s0, m1[0]));
                m2[1] = fminf(m2[1], fmaxf(s1, m1[1]));
                ki[0] = lt0 ? (kb + j) : ki[0];
                ki[1] = lt1 ? (kb + j) : ki[1];
                m1[0] = fminf(m1[0], s0);
                m1[1] = fminf(m1[1], s1);
            }
        }
        __syncthreads();
    }

#pragma unroll
    for (int d = 16; d <= 32; d <<= 1) {
#pragma unroll
        for (int tt = 0; tt < 2; ++tt) {
            float om1 = __shfl_xor(m1[tt], d, 64);
            float om2 = __shfl_xor(m2[tt], d, 64);
            int   oki = __shfl_xor(ki[tt], d, 64);
            m2[tt] = fminf(fminf(m2[tt], om2), fmaxf(m1[tt], om1));
            ki[tt] = (om1 < m1[tt]) ? oki : ki[tt];
            m1[tt] = fminf(m1[tt], om1);
        }
    }

    // ---- Phase 2: in-wave exact rescue of flagged tokens ----
    // mask bit b (0..31): token tbase + (b>>4)*16 + (b&15)
    unsigned long long b0 = __ballot((lane < 16) && (m2[0] - m1[0] < EPS_FLAG));
    unsigned long long b1 = __ballot((lane < 16) && (m2[1] - m1[1] < EPS_FLAG));
    unsigned mask = (unsigned)(b0 & 0xFFFFull) | (((unsigned)(b1 & 0xFFFFull)) << 16);

    float* zrow = (float*)(lds + 33280) + wid * 64;
    const float4* cbT4 = (const float4*)cbT;
    const float4* h4   = (const float4*)h_g;

    while (mask) {
        const int b = __builtin_ctz(mask);
        mask &= mask - 1;
        const int t = tbase + (b >> 4) * 16 + (b & 15);

        zrow[lane] = ze[(size_t)t * 64 + lane];
        __builtin_amdgcn_wave_barrier();
        asm volatile("s_waitcnt lgkmcnt(0)" ::: "memory");

        float sz;
#define GZ(d) (zrow[d])
        NP_PAIRWISE_SQ64(GZ, sz);
#undef GZ

        unsigned long long key = ~0ull;
        for (int s = 0; s < 4; ++s) {
            const int kc = s * 64 + lane;   // float4 index: codes 4kc..4kc+3
            float a0 = 0.f, a1 = 0.f, a2 = 0.f, a3 = 0.f;
#pragma unroll 8
            for (int d = 0; d < 64; ++d) {
                float zd = zrow[d];
                float4 cv = cbT4[d * 256 + kc];
                a0 = fmaf(cv.x, zd, a0); a1 = fmaf(cv.y, zd, a1);
                a2 = fmaf(cv.z, zd, a2); a3 = fmaf(cv.w, zd, a3);
            }
            float4 hv = h4[kc];
            float dk0 = (sz + hv.x) - 2.0f * a0;
            float dk1 = (sz + hv.y) - 2.0f * a1;
            float dk2 = (sz + hv.z) - 2.0f * a2;
            float dk3 = (sz + hv.w) - 2.0f * a3;
            unsigned kbase = 4u * (unsigned)kc;
            unsigned long long c0 = ((unsigned long long)__float_as_uint(dk0) << 32) | (kbase + 0);
            unsigned long long c1 = ((unsigned long long)__float_as_uint(dk1) << 32) | (kbase + 1);
            unsigned long long c2 = ((unsigned long long)__float_as_uint(dk2) << 32) | (kbase + 2);
            unsigned long long c3 = ((unsigned long long)__float_as_uint(dk3) << 32) | (kbase + 3);
            key = c0 < key ? c0 : key;
            key = c1 < key ? c1 : key;
            key = c2 < key ? c2 : key;
            key = c3 < key ? c3 : key;
        }
#pragma unroll
        for (int dd = 1; dd < 64; dd <<= 1) {
            unsigned long long o = __shfl_xor(key, dd, 64);
            key = o < key ? o : key;
        }
        if (lane == (b & 15)) ki[b >> 4] = (int)(unsigned)(key & 0xFFFFFFFFull);
    }

    // ---- Phase 3: gather z_q_st, idx write, fp64 SSE, histogram ----
    double lsse = 0.0;
    for (int w = 0; w < 32; ++w) {
        const int tt = w >> 4, i = w & 15;
        const int idx = __shfl(ki[tt], i, 64);       // wave-uniform
        const int t = tbase + tt * 16 + i;
        float q  = cb[idx * 64 + lane];
        float zv = ze[(size_t)t * 64 + lane];
        out[(size_t)t * 64 + lane] = q;
        double diff = (double)q - (double)zv;
        lsse = fma(diff, diff, lsse);
        if (lane == 0) {
            out[OUT_IDX + t] = (float)idx;
            atomicAdd(&counts[idx], 1);
        }
    }
#pragma unroll
    for (int off = 32; off > 0; off >>= 1)
        lsse += __shfl_down(lsse, off, 64);

    double* red = (double*)(lds + 35328);
    int* flag = (int*)(lds + 35392);
    if (lane == 0) red[wid] = lsse;
    __syncthreads();
    if (tid == 0) {
        double bs = ((red[0] + red[1]) + (red[2] + red[3]))
                  + ((red[4] + red[5]) + (red[6] + red[7]));
        atomicAdd(sse_g, bs);
        __threadfence();
        int v = atomicAdd(done, 1);
        *flag = (v == (int)gridDim.x - 1);
    }
    __syncthreads();

    // ---- Phase 4: last block finalizes loss + perplexity ----
    if (*flag) {
        __threadfence();
        double* red2 = (double*)lds;   // staging LDS is dead; reuse as double[512]
        double local = 0.0;
        for (int k = tid; k < NEMB; k += 512) {
            int cv = __hip_atomic_load(&counts[k], __ATOMIC_RELAXED, __HIP_MEMORY_SCOPE_AGENT);
            double p = (double)cv / (double)NTOK;
            local += p * log(p + 1e-10);
        }
        red2[tid] = local;
        __syncthreads();
        for (int s = 256; s > 0; s >>= 1) {
            if (tid < s) red2[tid] += red2[tid + s];
            __syncthreads();
        }
        if (tid == 0) {
            double sv = __hip_atomic_load(sse_g, __ATOMIC_RELAXED, __HIP_MEMORY_SCOPE_AGENT);
            double mse = sv / ((double)NTOK * (double)DIM);
            out[OUT_LOSS] = (float)(1.25 * mse);
            out[OUT_PERP] = (float)exp(-red2[0]);
        }
    }
}

extern "C" void kernel_launch(void* const* d_in, const int* in_sizes, int n_in,
                              void* d_out, int out_size, void* d_ws, size_t ws_size,
                              hipStream_t stream) {
    const float* ze = (const float*)d_in[0];
    const float* cb = (const float*)d_in[1];
    float* out = (float*)d_out;

    char* w = (char*)d_ws;
    double*         sse    = (double*)w;                    // @0
    int*            counts = (int*)(w + 64);                // @64    (4 KiB)
    int*            done   = (int*)(w + 4160);              // @4160
    float*          h      = (float*)(w + 4224);            // @4224  (4 KiB)
    unsigned short* ch     = (unsigned short*)(w + 8320);   // 128 KiB
    unsigned short* cl     = (unsigned short*)(w + 139392); // 128 KiB
    float*          cbT    = (float*)(w + 270464);          // 256 KiB

    vq_prep<<<NEMB / 256, 256, 0, stream>>>(cb, h, ch, cl, cbT, sse, counts, done);
    vq_fused<<<NTOK / 256, 512, 0, stream>>>(ze, cb, ch, cl, h, cbT, out, sse, counts, done);
}

// Round 8
// 179.959 us; speedup vs baseline: 1.7507x; 1.7507x over previous
//
#include <hip/hip_runtime.h>
#include <math.h>

// VectorQuantizer: N=131072 tokens, K=1024 codes, D=64, fp32.
// Out layout (flat): z_q_st[N*D] | loss | perplexity | indices[N] (as f32)
#define NTOK 131072
#define NEMB 1024
#define DIM  64
#define OUT_LOSS (NTOK * DIM)
#define OUT_PERP (OUT_LOSS + 1)
#define OUT_IDX  (OUT_LOSS + 2)

#define EPS_FLAG 6e-5f   // screen ambiguity margin (frozen; passed r3-r7)

typedef short bf16x8 __attribute__((ext_vector_type(8)));
typedef float f32x4  __attribute__((ext_vector_type(4)));

// ---- numpy fp32 semantics helpers (frozen from round 2 -- PASSED) ----------
__device__ __forceinline__ float sqb(float x) {
    float y = x * x;
    asm volatile("" : "+v"(y));
    return y;
}
// numpy pairwise_sum for n=64 contiguous: 8 accumulators stride 8, then
// ((r0+r1)+(r2+r3))+((r4+r5)+(r6+r7)).
#define NP_PAIRWISE_SQ64(GET, RES)                                     \
    do {                                                               \
        float r0 = sqb(GET(0)), r1 = sqb(GET(1)), r2 = sqb(GET(2)),    \
              r3 = sqb(GET(3)), r4 = sqb(GET(4)), r5 = sqb(GET(5)),    \
              r6 = sqb(GET(6)), r7 = sqb(GET(7));                      \
        _Pragma("unroll")                                              \
        for (int i = 8; i < 64; i += 8) {                              \
            r0 += sqb(GET(i + 0)); r1 += sqb(GET(i + 1));              \
            r2 += sqb(GET(i + 2)); r3 += sqb(GET(i + 3));              \
            r4 += sqb(GET(i + 4)); r5 += sqb(GET(i + 5));              \
            r6 += sqb(GET(i + 6)); r7 += sqb(GET(i + 7));              \
        }                                                              \
        RES = ((r0 + r1) + (r2 + r3)) + ((r4 + r5) + (r6 + r7));       \
    } while (0)

__device__ __forceinline__ unsigned short f2bf_rne(float x) {
    unsigned u = __float_as_uint(x);
    u += 0x7FFFu + ((u >> 16) & 1u);   // round-to-nearest-even
    return (unsigned short)(u >> 16);
}
__device__ __forceinline__ float bf2f(unsigned short b) {
    return __uint_as_float(((unsigned)b) << 16);
}

// ws layout (bytes):
//   0:      sse double
//   64:     counts int[1024]
//   4160:   qcount int
//   4224:   h float[1024]
//   8320:   ch bf16[1024*64]   (128 KiB)
//   139392: cl bf16[1024*64]   (128 KiB)
//   270464: qlist int[NTOK]    (512 KiB)

// Kernel 0: h[k] np-exact; ch/cl bf16 split of (-2c); block 0 zeroes accums.
__global__ void vq_prep(const float* __restrict__ cb, float* __restrict__ h,
                        unsigned short* __restrict__ ch, unsigned short* __restrict__ cl,
                        double* __restrict__ sse, int* __restrict__ counts,
                        int* __restrict__ qcount) {
    if (blockIdx.x == 0) {
        if (threadIdx.x == 0) { *sse = 0.0; *qcount = 0; }
        for (int i = threadIdx.x; i < NEMB; i += 256) counts[i] = 0;
    }
    int k = blockIdx.x * 256 + threadIdx.x;
    if (k >= NEMB) return;
    float c[64];
    const float4* p = (const float4*)(cb + k * DIM);
#pragma unroll
    for (int q = 0; q < 16; ++q) {
        float4 v = p[q];
        c[4 * q] = v.x; c[4 * q + 1] = v.y; c[4 * q + 2] = v.z; c[4 * q + 3] = v.w;
    }
    float hk;
#define GETC(d) (c[d])
    NP_PAIRWISE_SQ64(GETC, hk);
#undef GETC
    h[k] = hk;
#pragma unroll
    for (int b = 0; b < 8; ++b) {
        unsigned uhv[4], ulv[4];
#pragma unroll
        for (int e = 0; e < 4; ++e) {
            float x0 = -2.0f * c[b * 8 + e * 2 + 0];
            float x1 = -2.0f * c[b * 8 + e * 2 + 1];
            unsigned short h0 = f2bf_rne(x0), h1 = f2bf_rne(x1);
            unsigned short l0 = f2bf_rne(x0 - bf2f(h0)), l1 = f2bf_rne(x1 - bf2f(h1));
            uhv[e] = (unsigned)h0 | ((unsigned)h1 << 16);
            ulv[e] = (unsigned)l0 | ((unsigned)l1 << 16);
        }
        *(uint4*)(ch + k * 64 + b * 8) = make_uint4(uhv[0], uhv[1], uhv[2], uhv[3]);
        *(uint4*)(cl + k * 64 + b * 8) = make_uint4(ulv[0], ulv[1], ulv[2], ulv[3]);
    }
}

// Kernel 1: MFMA screen (byte-frozen from r4 -- PASSED r4/r5/r6/r7).
__global__ __launch_bounds__(512) void vq_screen(
    const float*          __restrict__ ze,
    const unsigned short* __restrict__ ch_g,
    const unsigned short* __restrict__ cl_g,
    const float*          __restrict__ h_g,
    float*                __restrict__ out,
    int*                  __restrict__ qcount,
    int*                  __restrict__ qlist) {
    __shared__ __align__(16) char lds[2 * 16384 + 2 * 256];
    const int tid  = threadIdx.x;
    const int lane = tid & 63;
    const int wid  = tid >> 6;
    const int col  = lane & 15;
    const int grp  = lane >> 4;
    const int tbase = blockIdx.x * 256 + wid * 32;

    bf16x8 zh[2][2], zl[2][2];
#pragma unroll
    for (int tt = 0; tt < 2; ++tt)
#pragma unroll
        for (int s = 0; s < 2; ++s) {
            const float* zp = ze + (size_t)(tbase + tt * 16 + col) * 64 + s * 32 + grp * 8;
            float4 v0 = *(const float4*)(zp);
            float4 v1 = *(const float4*)(zp + 4);
            float zv[8] = {v0.x, v0.y, v0.z, v0.w, v1.x, v1.y, v1.z, v1.w};
            bf16x8 hfr, lfr;
#pragma unroll
            for (int j = 0; j < 8; ++j) {
                unsigned short hb = f2bf_rne(zv[j]);
                unsigned short lb = f2bf_rne(zv[j] - bf2f(hb));
                hfr[j] = (short)hb;
                lfr[j] = (short)lb;
            }
            zh[tt][s] = hfr;
            zl[tt][s] = lfr;
        }

    float m1[2] = {INFINITY, INFINITY}, m2[2] = {INFINITY, INFINITY};
    int   ki[2] = {0, 0};

#define STAGE(cc, b)                                                            \
    do {                                                                        \
        int i = tid;                                                            \
        int4 va = *(const int4*)((const char*)ch_g + (cc) * 8192 + i * 16);     \
        int4 vb = *(const int4*)((const char*)cl_g + (cc) * 8192 + i * 16);     \
        int r = i >> 3, slot = i & 7;                                           \
        int st = r >> 4, row = r & 15;                                          \
        int off = (b) * 16384 + st * 2048 + row * 128 + ((slot ^ (row & 7)) << 4); \
        *(int4*)(lds + off) = va;                                               \
        *(int4*)(lds + off + 8192) = vb;                                        \
        if (i < 64) *(float*)(lds + 32768 + (b) * 256 + i * 4) = h_g[(cc) * 64 + i]; \
    } while (0)

    STAGE(0, 0);
    __syncthreads();

    for (int cc = 0; cc < 16; ++cc) {
        int b = cc & 1;
        if (cc + 1 < 16) STAGE(cc + 1, b ^ 1);

        for (int ct = 0; ct < 4; ++ct) {
            const int arow = b * 16384 + ct * 2048 + col * 128;
            bf16x8 ach0 = *(const bf16x8*)(lds + arow + ((((0 * 4) + grp) ^ (col & 7)) << 4));
            bf16x8 ach1 = *(const bf16x8*)(lds + arow + ((((1 * 4) + grp) ^ (col & 7)) << 4));
            bf16x8 acl0 = *(const bf16x8*)(lds + arow + 8192 + ((((0 * 4) + grp) ^ (col & 7)) << 4));
            bf16x8 acl1 = *(const bf16x8*)(lds + arow + 8192 + ((((1 * 4) + grp) ^ (col & 7)) << 4));
            f32x4 hv = *(const f32x4*)(lds + 32768 + b * 256 + ct * 64 + grp * 16);

            f32x4 acc0 = hv, acc1 = hv;
            acc0 = __builtin_amdgcn_mfma_f32_16x16x32_bf16(ach0, zh[0][0], acc0, 0, 0, 0);
            acc1 = __builtin_amdgcn_mfma_f32_16x16x32_bf16(ach0, zh[1][0], acc1, 0, 0, 0);
            acc0 = __builtin_amdgcn_mfma_f32_16x16x32_bf16(ach1, zh[0][1], acc0, 0, 0, 0);
            acc1 = __builtin_amdgcn_mfma_f32_16x16x32_bf16(ach1, zh[1][1], acc1, 0, 0, 0);
            acc0 = __builtin_amdgcn_mfma_f32_16x16x32_bf16(ach0, zl[0][0], acc0, 0, 0, 0);
            acc1 = __builtin_amdgcn_mfma_f32_16x16x32_bf16(ach0, zl[1][0], acc1, 0, 0, 0);
            acc0 = __builtin_amdgcn_mfma_f32_16x16x32_bf16(ach1, zl[0][1], acc0, 0, 0, 0);
            acc1 = __builtin_amdgcn_mfma_f32_16x16x32_bf16(ach1, zl[1][1], acc1, 0, 0, 0);
            acc0 = __builtin_amdgcn_mfma_f32_16x16x32_bf16(acl0, zh[0][0], acc0, 0, 0, 0);
            acc1 = __builtin_amdgcn_mfma_f32_16x16x32_bf16(acl0, zh[1][0], acc1, 0, 0, 0);
            acc0 = __builtin_amdgcn_mfma_f32_16x16x32_bf16(acl1, zh[0][1], acc0, 0, 0, 0);
            acc1 = __builtin_amdgcn_mfma_f32_16x16x32_bf16(acl1, zh[1][1], acc1, 0, 0, 0);

            const int kb = cc * 64 + ct * 16 + grp * 4;
#pragma unroll
            for (int j = 0; j < 4; ++j) {
                float s0 = acc0[j], s1 = acc1[j];
                bool lt0 = s0 < m1[0], lt1 = s1 < m1[1];
                m2[0] = fminf(m2[0], fmaxf(s0, m1[0]));
                m2[1] = fminf(m2[1], fmaxf(s1, m1[1]));
                ki[0] = lt0 ? (kb + j) : ki[0];
                ki[1] = lt1 ? (kb + j) : ki[1];
                m1[0] = fminf(m1[0], s0);
                m1[1] = fminf(m1[1], s1);
            }
        }
        __syncthreads();
    }

#pragma unroll
    for (int d = 16; d <= 32; d <<= 1) {
#pragma unroll
        for (int tt = 0; tt < 2; ++tt) {
            float om1 = __shfl_xor(m1[tt], d, 64);
            float om2 = __shfl_xor(m2[tt], d, 64);
            int   oki = __shfl_xor(ki[tt], d, 64);
            m2[tt] = fminf(fminf(m2[tt], om2), fmaxf(m1[tt], om1));
            ki[tt] = (om1 < m1[tt]) ? oki : ki[tt];
            m1[tt] = fminf(m1[tt], om1);
        }
    }
    if (lane < 16) {
#pragma unroll
        for (int tt = 0; tt < 2; ++tt) {
            int t = tbase + tt * 16 + lane;
            out[OUT_IDX + t] = (float)ki[tt];
            if (m2[tt] - m1[tt] < EPS_FLAG) {
                int slot = atomicAdd(qcount, 1);
                qlist[slot] = t;
            }
        }
    }
}

// Kernel 2: exact rescue, LDS-staged. 256 blocks x 512 thr, 1 block/CU.
// Block stages half the fp32 codebook (512 rows, row pad 17 float4) into LDS,
// scans its qlist slice from LDS (no per-token global latency chains), then
// restages the other half; per-token partial (d,k) keys persist in LDS.
__global__ __launch_bounds__(512) void vq_rescue(
    const float* __restrict__ ze, const float* __restrict__ cb,
    const float* __restrict__ h_g, const int* __restrict__ qcount,
    const int* __restrict__ qlist, float* __restrict__ out) {
    __shared__ __align__(16) float4 cbl[512 * 17];          // 139,264 B
    __shared__ float zst[8][64];                             // 2 KiB
    __shared__ unsigned long long keys[8][64];               // 4 KiB
    __shared__ float hl[NEMB];                               // 4 KiB
    const int tid  = threadIdx.x;
    const int lane = tid & 63;
    const int wid  = tid >> 6;
    const int nq   = *qcount;
    const int per  = (nq + 255) >> 8;
    const int i0   = blockIdx.x * per;
    const int iend = (i0 + per < nq) ? (i0 + per) : nq;
    if (i0 >= iend) return;   // uniform whole-block exit

    for (int i = tid; i < NEMB; i += 512) hl[i] = h_g[i];
    const float4* cb4 = (const float4*)cb;

    for (int hf = 0; hf < 2; ++hf) {
        __syncthreads();
        // stage 512 codes (coalesced reads; padded LDS rows)
#pragma unroll
        for (int j = 0; j < 16; ++j) {
            int f = tid + j * 512;            // 0..8191 float4s
            int code = f >> 4, d4 = f & 15;
            cbl[code * 17 + d4] = cb4[(size_t)(hf * 512 + code) * 16 + d4];
        }
        __syncthreads();

        for (int i = i0 + wid; i < iend; i += 8) {
            const int t = qlist[i];
            const int slot = (i - i0) >> 3;

            zst[wid][lane] = ze[(size_t)t * 64 + lane];
            __builtin_amdgcn_wave_barrier();
            asm volatile("s_waitcnt lgkmcnt(0)" ::: "memory");
            __builtin_amdgcn_sched_barrier(0);

            float sz;
#define GZ(d) (zst[wid][d])
            NP_PAIRWISE_SQ64(GZ, sz);
#undef GZ

            float acc[8] = {0.f, 0.f, 0.f, 0.f, 0.f, 0.f, 0.f, 0.f};
            const float4* zr4 = (const float4*)zst[wid];
#pragma unroll
            for (int d4 = 0; d4 < 16; ++d4) {
                float4 zq = zr4[d4];   // wave-broadcast
#pragma unroll
                for (int cc = 0; cc < 8; ++cc) {
                    float4 cv = cbl[(lane + 64 * cc) * 17 + d4];
                    acc[cc] = fmaf(cv.x, zq.x, acc[cc]);
                    acc[cc] = fmaf(cv.y, zq.y, acc[cc]);
                    acc[cc] = fmaf(cv.z, zq.z, acc[cc]);
                    acc[cc] = fmaf(cv.w, zq.w, acc[cc]);
                }
            }
            unsigned long long key = ~0ull;
#pragma unroll
            for (int cc = 0; cc < 8; ++cc) {
                unsigned k = (unsigned)(hf * 512 + lane + 64 * cc);
                float dk = (sz + hl[k]) - 2.0f * acc[cc];   // frozen np formula
                unsigned long long c =
                    ((unsigned long long)__float_as_uint(dk) << 32) | k;
                key = c < key ? c : key;
            }
#pragma unroll
            for (int dd = 1; dd < 64; dd <<= 1) {
                unsigned long long o = __shfl_xor(key, dd, 64);
                key = o < key ? o : key;
            }
            if (lane == 0) {
                if (hf == 0) {
                    keys[wid][slot] = key;
                } else {
                    unsigned long long k0 = keys[wid][slot];
                    if (k0 < key) key = k0;
                    out[OUT_IDX + t] = (float)(unsigned)(key & 0xFFFFFFFFull);
                }
            }
        }
    }
}

// Kernel 3: gather z_q_st, fp64 SSE, histogram (byte-frozen from r4).
__global__ __launch_bounds__(256) void vq_gather(
    const float* __restrict__ ze, const float* __restrict__ cb,
    float* __restrict__ out, double* __restrict__ sse_g, int* __restrict__ counts) {
    const int base = blockIdx.x * 256 + threadIdx.x;
    const int stride = 2048 * 256;
    double lsse = 0.0;
#pragma unroll
    for (int it = 0; it < 16; ++it) {
        int gid = base + it * stride;
        int n = gid >> 6, d = gid & 63;
        int idx = (int)out[OUT_IDX + n];
        float q = cb[idx * DIM + d];
        float zv = ze[gid];
        out[gid] = q;
        if (d == 0) atomicAdd(&counts[idx], 1);
        double diff = (double)q - (double)zv;
        lsse = fma(diff, diff, lsse);
    }
#pragma unroll
    for (int off = 32; off > 0; off >>= 1)
        lsse += __shfl_down(lsse, off, 64);
    __shared__ double red[4];
    if ((threadIdx.x & 63) == 0) red[threadIdx.x >> 6] = lsse;
    __syncthreads();
    if (threadIdx.x == 0)
        atomicAdd(sse_g, (red[0] + red[1]) + (red[2] + red[3]));
}

// Kernel 4: finalize loss (= 1.25*MSE) and perplexity. (frozen)
__global__ void vq_finalize(const double* __restrict__ sse_g,
                            const int* __restrict__ counts,
                            float* __restrict__ out) {
    __shared__ double red[256];
    int tid = threadIdx.x;
    double local = 0.0;
    for (int k = tid; k < NEMB; k += 256) {
        double p = (double)counts[k] / (double)NTOK;
        local += p * log(p + 1e-10);
    }
    red[tid] = local;
    __syncthreads();
    for (int s = 128; s > 0; s >>= 1) {
        if (tid < s) red[tid] += red[tid + s];
        __syncthreads();
    }
    if (tid == 0) {
        double mse = *sse_g / ((double)NTOK * (double)DIM);
        out[OUT_LOSS] = (float)(1.25 * mse);
        out[OUT_PERP] = (float)exp(-red[0]);
    }
}

extern "C" void kernel_launch(void* const* d_in, const int* in_sizes, int n_in,
                              void* d_out, int out_size, void* d_ws, size_t ws_size,
                              hipStream_t stream) {
    const float* ze = (const float*)d_in[0];
    const float* cb = (const float*)d_in[1];
    float* out = (float*)d_out;

    char* w = (char*)d_ws;
    double*         sse    = (double*)w;                    // @0
    int*            counts = (int*)(w + 64);                // @64    (4 KiB)
    int*            qcount = (int*)(w + 4160);              // @4160
    float*          h      = (float*)(w + 4224);            // @4224  (4 KiB)
    unsigned short* ch     = (unsigned short*)(w + 8320);   // 128 KiB
    unsigned short* cl     = (unsigned short*)(w + 139392); // 128 KiB
    int*            qlist  = (int*)(w + 270464);            // 512 KiB

    vq_prep<<<NEMB / 256, 256, 0, stream>>>(cb, h, ch, cl, sse, counts, qcount);
    vq_screen<<<NTOK / 256, 512, 0, stream>>>(ze, ch, cl, h, out, qcount, qlist);
    vq_rescue<<<256, 512, 0, stream>>>(ze, cb, h, qcount, qlist, out);
    vq_gather<<<2048, 256, 0, stream>>>(ze, cb, out, sse, counts);
    vq_finalize<<<1, 256, 0, stream>>>(sse, counts, out);
}

// Round 9
// 174.816 us; speedup vs baseline: 1.8022x; 1.0294x over previous
//
#include <hip/hip_runtime.h>
#include <math.h>

// VectorQuantizer: N=131072 tokens, K=1024 codes, D=64, fp32.
// Out layout (flat): z_q_st[N*D] | loss | perplexity | indices[N] (as f32)
#define NTOK 131072
#define NEMB 1024
#define DIM  64
#define OUT_LOSS (NTOK * DIM)
#define OUT_PERP (OUT_LOSS + 1)
#define OUT_IDX  (OUT_LOSS + 2)

#define EPS_FLAG 6e-5f   // screen ambiguity margin (frozen; passed r3-r8)

typedef short bf16x8 __attribute__((ext_vector_type(8)));
typedef float f32x4  __attribute__((ext_vector_type(4)));

// ---- numpy fp32 semantics helpers (frozen from round 2 -- PASSED) ----------
__device__ __forceinline__ float sqb(float x) {
    float y = x * x;
    asm volatile("" : "+v"(y));
    return y;
}
// numpy pairwise_sum for n=64 contiguous: 8 accumulators stride 8, then
// ((r0+r1)+(r2+r3))+((r4+r5)+(r6+r7)).
#define NP_PAIRWISE_SQ64(GET, RES)                                     \
    do {                                                               \
        float r0 = sqb(GET(0)), r1 = sqb(GET(1)), r2 = sqb(GET(2)),    \
              r3 = sqb(GET(3)), r4 = sqb(GET(4)), r5 = sqb(GET(5)),    \
              r6 = sqb(GET(6)), r7 = sqb(GET(7));                      \
        _Pragma("unroll")                                              \
        for (int i = 8; i < 64; i += 8) {                              \
            r0 += sqb(GET(i + 0)); r1 += sqb(GET(i + 1));              \
            r2 += sqb(GET(i + 2)); r3 += sqb(GET(i + 3));              \
            r4 += sqb(GET(i + 4)); r5 += sqb(GET(i + 5));              \
            r6 += sqb(GET(i + 6)); r7 += sqb(GET(i + 7));              \
        }                                                              \
        RES = ((r0 + r1) + (r2 + r3)) + ((r4 + r5) + (r6 + r7));       \
    } while (0)

__device__ __forceinline__ unsigned short f2bf_rne(float x) {
    unsigned u = __float_as_uint(x);
    u += 0x7FFFu + ((u >> 16) & 1u);   // round-to-nearest-even
    return (unsigned short)(u >> 16);
}
__device__ __forceinline__ float bf2f(unsigned short b) {
    return __uint_as_float(((unsigned)b) << 16);
}

// ws layout (bytes):
//   0:      sse double
//   64:     counts int[1024]
//   4160:   qcount int
//   4168:   done int
//   4224:   h float[1024]
//   8320:   ch bf16[1024*64]   (128 KiB)
//   139392: cl bf16[1024*64]   (128 KiB)
//   270464: qlist int[NTOK]    (512 KiB)

// Kernel 0: h[k] np-exact; ch/cl bf16 split of (-2c); block 0 zeroes accums.
__global__ void vq_prep(const float* __restrict__ cb, float* __restrict__ h,
                        unsigned short* __restrict__ ch, unsigned short* __restrict__ cl,
                        double* __restrict__ sse, int* __restrict__ counts,
                        int* __restrict__ qcount, int* __restrict__ done) {
    if (blockIdx.x == 0) {
        if (threadIdx.x == 0) { *sse = 0.0; *qcount = 0; *done = 0; }
        for (int i = threadIdx.x; i < NEMB; i += 256) counts[i] = 0;
    }
    int k = blockIdx.x * 256 + threadIdx.x;
    if (k >= NEMB) return;
    float c[64];
    const float4* p = (const float4*)(cb + k * DIM);
#pragma unroll
    for (int q = 0; q < 16; ++q) {
        float4 v = p[q];
        c[4 * q] = v.x; c[4 * q + 1] = v.y; c[4 * q + 2] = v.z; c[4 * q + 3] = v.w;
    }
    float hk;
#define GETC(d) (c[d])
    NP_PAIRWISE_SQ64(GETC, hk);
#undef GETC
    h[k] = hk;
#pragma unroll
    for (int b = 0; b < 8; ++b) {
        unsigned uhv[4], ulv[4];
#pragma unroll
        for (int e = 0; e < 4; ++e) {
            float x0 = -2.0f * c[b * 8 + e * 2 + 0];
            float x1 = -2.0f * c[b * 8 + e * 2 + 1];
            unsigned short h0 = f2bf_rne(x0), h1 = f2bf_rne(x1);
            unsigned short l0 = f2bf_rne(x0 - bf2f(h0)), l1 = f2bf_rne(x1 - bf2f(h1));
            uhv[e] = (unsigned)h0 | ((unsigned)h1 << 16);
            ulv[e] = (unsigned)l0 | ((unsigned)l1 << 16);
        }
        *(uint4*)(ch + k * 64 + b * 8) = make_uint4(uhv[0], uhv[1], uhv[2], uhv[3]);
        *(uint4*)(cl + k * 64 + b * 8) = make_uint4(ulv[0], ulv[1], ulv[2], ulv[3]);
    }
}

// Kernel 1: MFMA screen (frozen MFMA numerics) + T14 async staging +
// per-j ILP min-slots + fused gather/SSE/histogram epilogue.
__global__ __launch_bounds__(512) void vq_screen(
    const float*          __restrict__ ze,
    const float*          __restrict__ cb,
    const unsigned short* __restrict__ ch_g,
    const unsigned short* __restrict__ cl_g,
    const float*          __restrict__ h_g,
    float*                __restrict__ out,
    int*                  __restrict__ qcount,
    int*                  __restrict__ qlist,
    double*               __restrict__ sse_g,
    int*                  __restrict__ counts) {
    __shared__ __align__(16) char lds[33280 + 64];
    const int tid  = threadIdx.x;
    const int lane = tid & 63;
    const int wid  = tid >> 6;
    const int col  = lane & 15;
    const int grp  = lane >> 4;
    const int tbase = blockIdx.x * 256 + wid * 32;

    // z fragments (frozen)
    bf16x8 zh[2][2], zl[2][2];
#pragma unroll
    for (int tt = 0; tt < 2; ++tt)
#pragma unroll
        for (int s = 0; s < 2; ++s) {
            const float* zp = ze + (size_t)(tbase + tt * 16 + col) * 64 + s * 32 + grp * 8;
            float4 v0 = *(const float4*)(zp);
            float4 v1 = *(const float4*)(zp + 4);
            float zv[8] = {v0.x, v0.y, v0.z, v0.w, v1.x, v1.y, v1.z, v1.w};
            bf16x8 hfr, lfr;
#pragma unroll
            for (int j = 0; j < 8; ++j) {
                unsigned short hb = f2bf_rne(zv[j]);
                unsigned short lb = f2bf_rne(zv[j] - bf2f(hb));
                hfr[j] = (short)hb;
                lfr[j] = (short)lb;
            }
            zh[tt][s] = hfr;
            zl[tt][s] = lfr;
        }

    // per-j independent min slots (ILP): 4 chains per token tile
    float s1[2][4], s2[2][4];
    int   sk[2][4];
#pragma unroll
    for (int tt = 0; tt < 2; ++tt)
#pragma unroll
        for (int j = 0; j < 4; ++j) {
            s1[tt][j] = INFINITY; s2[tt][j] = INFINITY; sk[tt][j] = 0;
        }

    // T14 split staging: LOADR issues global loads; WRITER lands them in LDS.
    int4 va, vb; float hval = 0.f;
#define LOADR(cc)                                                          \
    do {                                                                   \
        va = *(const int4*)((const char*)ch_g + (cc) * 8192 + tid * 16);   \
        vb = *(const int4*)((const char*)cl_g + (cc) * 8192 + tid * 16);   \
        if (tid < 64) hval = h_g[(cc) * 64 + tid];                         \
    } while (0)
#define WRITER(b)                                                          \
    do {                                                                   \
        int r = tid >> 3, slot = tid & 7;                                  \
        int st = r >> 4, row = r & 15;                                     \
        int off = (b) * 16384 + st * 2048 + row * 128 + ((slot ^ (row & 7)) << 4); \
        *(int4*)(lds + off) = va;                                          \
        *(int4*)(lds + off + 8192) = vb;                                   \
        if (tid < 64) *(float*)(lds + 32768 + (b) * 256 + tid * 4) = hval; \
    } while (0)

    LOADR(0); WRITER(0);
    __syncthreads();

    for (int cc = 0; cc < 16; ++cc) {
        int b = cc & 1;
        if (cc < 15) LOADR(cc + 1);   // issue early (hidden under MFMA phase)

        for (int ct = 0; ct < 4; ++ct) {
            const int arow = b * 16384 + ct * 2048 + col * 128;
            bf16x8 ach0 = *(const bf16x8*)(lds + arow + ((((0 * 4) + grp) ^ (col & 7)) << 4));
            bf16x8 ach1 = *(const bf16x8*)(lds + arow + ((((1 * 4) + grp) ^ (col & 7)) << 4));
            bf16x8 acl0 = *(const bf16x8*)(lds + arow + 8192 + ((((0 * 4) + grp) ^ (col & 7)) << 4));
            bf16x8 acl1 = *(const bf16x8*)(lds + arow + 8192 + ((((1 * 4) + grp) ^ (col & 7)) << 4));
            f32x4 hv = *(const f32x4*)(lds + 32768 + b * 256 + ct * 64 + grp * 16);

            f32x4 acc0 = hv, acc1 = hv;
            acc0 = __builtin_amdgcn_mfma_f32_16x16x32_bf16(ach0, zh[0][0], acc0, 0, 0, 0);
            acc1 = __builtin_amdgcn_mfma_f32_16x16x32_bf16(ach0, zh[1][0], acc1, 0, 0, 0);
            acc0 = __builtin_amdgcn_mfma_f32_16x16x32_bf16(ach1, zh[0][1], acc0, 0, 0, 0);
            acc1 = __builtin_amdgcn_mfma_f32_16x16x32_bf16(ach1, zh[1][1], acc1, 0, 0, 0);
            acc0 = __builtin_amdgcn_mfma_f32_16x16x32_bf16(ach0, zl[0][0], acc0, 0, 0, 0);
            acc1 = __builtin_amdgcn_mfma_f32_16x16x32_bf16(ach0, zl[1][0], acc1, 0, 0, 0);
            acc0 = __builtin_amdgcn_mfma_f32_16x16x32_bf16(ach1, zl[0][1], acc0, 0, 0, 0);
            acc1 = __builtin_amdgcn_mfma_f32_16x16x32_bf16(ach1, zl[1][1], acc1, 0, 0, 0);
            acc0 = __builtin_amdgcn_mfma_f32_16x16x32_bf16(acl0, zh[0][0], acc0, 0, 0, 0);
            acc1 = __builtin_amdgcn_mfma_f32_16x16x32_bf16(acl0, zh[1][0], acc1, 0, 0, 0);
            acc0 = __builtin_amdgcn_mfma_f32_16x16x32_bf16(acl1, zh[0][1], acc0, 0, 0, 0);
            acc1 = __builtin_amdgcn_mfma_f32_16x16x32_bf16(acl1, zh[1][1], acc1, 0, 0, 0);

            const int kb = cc * 64 + ct * 16 + grp * 4;
#pragma unroll
            for (int j = 0; j < 4; ++j) {
                float v0 = acc0[j], v1 = acc1[j];
                s2[0][j] = fminf(s2[0][j], fmaxf(v0, s1[0][j]));
                sk[0][j] = (v0 < s1[0][j]) ? (kb + j) : sk[0][j];
                s1[0][j] = fminf(s1[0][j], v0);
                s2[1][j] = fminf(s2[1][j], fmaxf(v1, s1[1][j]));
                sk[1][j] = (v1 < s1[1][j]) ? (kb + j) : sk[1][j];
                s1[1][j] = fminf(s1[1][j], v1);
            }
        }
        if (cc < 15) WRITER(b ^ 1);   // vmcnt wait here, after compute
        __syncthreads();
    }

    // merge the 4 slots (second-min merge formula, proven in the lane reduce)
    float m1[2], m2[2]; int ki[2];
#pragma unroll
    for (int tt = 0; tt < 2; ++tt) {
        m1[tt] = s1[tt][0]; m2[tt] = s2[tt][0]; ki[tt] = sk[tt][0];
#pragma unroll
        for (int j = 1; j < 4; ++j) {
            m2[tt] = fminf(fminf(m2[tt], s2[tt][j]), fmaxf(m1[tt], s1[tt][j]));
            ki[tt] = (s1[tt][j] < m1[tt]) ? sk[tt][j] : ki[tt];
            m1[tt] = fminf(m1[tt], s1[tt][j]);
        }
    }

    // cross-lane-group reduce (frozen)
#pragma unroll
    for (int d = 16; d <= 32; d <<= 1) {
#pragma unroll
        for (int tt = 0; tt < 2; ++tt) {
            float om1 = __shfl_xor(m1[tt], d, 64);
            float om2 = __shfl_xor(m2[tt], d, 64);
            int   oki = __shfl_xor(ki[tt], d, 64);
            m2[tt] = fminf(fminf(m2[tt], om2), fmaxf(m1[tt], om1));
            ki[tt] = (om1 < m1[tt]) ? oki : ki[tt];
            m1[tt] = fminf(m1[tt], om1);
        }
    }
    if (lane < 16) {
#pragma unroll
        for (int tt = 0; tt < 2; ++tt) {
            int t = tbase + tt * 16 + lane;
            out[OUT_IDX + t] = (float)ki[tt];
            if (m2[tt] - m1[tt] < EPS_FLAG) {
                int slot = atomicAdd(qcount, 1);
                qlist[slot] = t;
            }
        }
    }

    // fused gather / SSE / histogram epilogue (r7 phase-3, verified)
    double lsse = 0.0;
    for (int w = 0; w < 32; ++w) {
        const int tt = w >> 4, i = w & 15;
        const int idx = __shfl(ki[tt], i, 64);   // wave-uniform
        const int t = tbase + tt * 16 + i;
        float q  = cb[idx * 64 + lane];
        float zv = ze[(size_t)t * 64 + lane];
        out[(size_t)t * 64 + lane] = q;
        double diff = (double)q - (double)zv;
        lsse = fma(diff, diff, lsse);
        if (lane == 0) atomicAdd(&counts[idx], 1);
    }
#pragma unroll
    for (int off = 32; off > 0; off >>= 1)
        lsse += __shfl_down(lsse, off, 64);
    double* red = (double*)(lds + 33280);
    if (lane == 0) red[wid] = lsse;
    __syncthreads();
    if (tid == 0) {
        double bs = ((red[0] + red[1]) + (red[2] + red[3]))
                  + ((red[4] + red[5]) + (red[6] + red[7]));
        atomicAdd(sse_g, bs);
    }
}

// Kernel 2: correction rescue (LDS-staged scan, r8 PASSED) + last-block
// finalize. Only tokens whose exact argmin differs from the screened idx get
// row-rewrite + counts/SSE fixup.
__global__ __launch_bounds__(512) void vq_rescue(
    const float* __restrict__ ze, const float* __restrict__ cb,
    const float* __restrict__ h_g, const int* __restrict__ qcount,
    const int* __restrict__ qlist, float* __restrict__ out,
    double* __restrict__ sse_g, int* __restrict__ counts,
    int* __restrict__ done) {
    __shared__ __align__(16) float4 cbl[512 * 17];          // 139,264 B
    __shared__ float zst[8][64];
    __shared__ unsigned long long keys[8][64];
    __shared__ float hl[NEMB];
    __shared__ int flagS;
    const int tid  = threadIdx.x;
    const int lane = tid & 63;
    const int wid  = tid >> 6;
    const int nq   = *qcount;
    const int per  = (nq + 255) >> 8;
    const int i0   = blockIdx.x * per;
    const int iend = (i0 + per < nq) ? (i0 + per) : nq;

    if (i0 < iend) {   // block-uniform
        for (int i = tid; i < NEMB; i += 512) hl[i] = h_g[i];
        const float4* cb4 = (const float4*)cb;

        for (int hf = 0; hf < 2; ++hf) {
            __syncthreads();
#pragma unroll
            for (int j = 0; j < 16; ++j) {
                int f = tid + j * 512;
                int code = f >> 4, d4 = f & 15;
                cbl[code * 17 + d4] = cb4[(size_t)(hf * 512 + code) * 16 + d4];
            }
            __syncthreads();

            for (int i = i0 + wid; i < iend; i += 8) {
                const int t = qlist[i];
                const int slot = (i - i0) >> 3;

                zst[wid][lane] = ze[(size_t)t * 64 + lane];
                __builtin_amdgcn_wave_barrier();
                asm volatile("s_waitcnt lgkmcnt(0)" ::: "memory");
                __builtin_amdgcn_sched_barrier(0);

                float sz;
#define GZ(d) (zst[wid][d])
                NP_PAIRWISE_SQ64(GZ, sz);
#undef GZ

                float acc[8] = {0.f, 0.f, 0.f, 0.f, 0.f, 0.f, 0.f, 0.f};
                const float4* zr4 = (const float4*)zst[wid];
#pragma unroll
                for (int d4 = 0; d4 < 16; ++d4) {
                    float4 zq = zr4[d4];
#pragma unroll
                    for (int cc = 0; cc < 8; ++cc) {
                        float4 cv = cbl[(lane + 64 * cc) * 17 + d4];
                        acc[cc] = fmaf(cv.x, zq.x, acc[cc]);
                        acc[cc] = fmaf(cv.y, zq.y, acc[cc]);
                        acc[cc] = fmaf(cv.z, zq.z, acc[cc]);
                        acc[cc] = fmaf(cv.w, zq.w, acc[cc]);
                    }
                }
                unsigned long long key = ~0ull;
#pragma unroll
                for (int cc = 0; cc < 8; ++cc) {
                    unsigned k = (unsigned)(hf * 512 + lane + 64 * cc);
                    float dk = (sz + hl[k]) - 2.0f * acc[cc];   // frozen formula
                    unsigned long long c =
                        ((unsigned long long)__float_as_uint(dk) << 32) | k;
                    key = c < key ? c : key;
                }
#pragma unroll
                for (int dd = 1; dd < 64; dd <<= 1) {
                    unsigned long long o = __shfl_xor(key, dd, 64);
                    key = o < key ? o : key;
                }
                if (hf == 0) {
                    if (lane == 0) keys[wid][slot] = key;
                } else {
                    unsigned long long k0 = keys[wid][slot];  // LDS broadcast
                    if (k0 < key) key = k0;
                    int newk = (int)(unsigned)(key & 0xFFFFFFFFull);
                    int scrk = (int)out[OUT_IDX + t];
                    if (newk != scrk) {
                        float zv = zst[wid][lane];
                        float qo = cb[scrk * 64 + lane];
                        float qn = cb[newk * 64 + lane];
                        out[(size_t)t * 64 + lane] = qn;
                        double dn = (double)qn - (double)zv;
                        double dd2 = (double)qo - (double)zv;
                        double delta = dn * dn - dd2 * dd2;
#pragma unroll
                        for (int off = 32; off > 0; off >>= 1)
                            delta += __shfl_down(delta, off, 64);
                        if (lane == 0) {
                            out[OUT_IDX + t] = (float)newk;
                            atomicAdd(sse_g, delta);
                            atomicAdd(&counts[scrk], -1);
                            atomicAdd(&counts[newk], 1);
                        }
                    }
                }
            }
        }
    }

    // all 256 blocks: done-counter; last block finalizes loss + perplexity
    __syncthreads();
    __threadfence();
    if (tid == 0) flagS = (atomicAdd(done, 1) == 255);
    __syncthreads();
    if (flagS) {
        __threadfence();
        double* red2 = (double*)cbl;   // staging LDS dead here
        double local = 0.0;
        for (int k = tid; k < NEMB; k += 512) {
            int cv = __hip_atomic_load(&counts[k], __ATOMIC_RELAXED, __HIP_MEMORY_SCOPE_AGENT);
            double p = (double)cv / (double)NTOK;
            local += p * log(p + 1e-10);
        }
        red2[tid] = local;
        __syncthreads();
        for (int s = 256; s > 0; s >>= 1) {
            if (tid < s) red2[tid] += red2[tid + s];
            __syncthreads();
        }
        if (tid == 0) {
            double sv = __hip_atomic_load(sse_g, __ATOMIC_RELAXED, __HIP_MEMORY_SCOPE_AGENT);
            double mse = sv / ((double)NTOK * (double)DIM);
            out[OUT_LOSS] = (float)(1.25 * mse);
            out[OUT_PERP] = (float)exp(-red2[0]);
        }
    }
}

extern "C" void kernel_launch(void* const* d_in, const int* in_sizes, int n_in,
                              void* d_out, int out_size, void* d_ws, size_t ws_size,
                              hipStream_t stream) {
    const float* ze = (const float*)d_in[0];
    const float* cb = (const float*)d_in[1];
    float* out = (float*)d_out;

    char* w = (char*)d_ws;
    double*         sse    = (double*)w;                    // @0
    int*            counts = (int*)(w + 64);                // @64    (4 KiB)
    int*            qcount = (int*)(w + 4160);              // @4160
    int*            done   = (int*)(w + 4168);              // @4168
    float*          h      = (float*)(w + 4224);            // @4224  (4 KiB)
    unsigned short* ch     = (unsigned short*)(w + 8320);   // 128 KiB
    unsigned short* cl     = (unsigned short*)(w + 139392); // 128 KiB
    int*            qlist  = (int*)(w + 270464);            // 512 KiB

    vq_prep<<<NEMB / 256, 256, 0, stream>>>(cb, h, ch, cl, sse, counts, qcount, done);
    vq_screen<<<NTOK / 256, 512, 0, stream>>>(ze, cb, ch, cl, h, out, qcount, qlist, sse, counts);
    vq_rescue<<<256, 512, 0, stream>>>(ze, cb, h, qcount, qlist, out, sse, counts, done);
}